// Round 13
// baseline (85.903 us; speedup 1.0000x reference)
//
#include <hip/hip_runtime.h>

#define BATCH 4096
#define DIM   512
#define NROW  8192
#define TILE  256
#define NCH   32                      // 256-row/col chunks
#define NBLK  (NCH * (NCH + 1) / 2)   // 528 triangle cells (incl. diagonal)
#define NSLOT 32

typedef __attribute__((ext_vector_type(8))) short bf16x8;
typedef __attribute__((ext_vector_type(4))) float f32x4;

__device__ inline unsigned short f2bf(float f) {
    unsigned int u = __float_as_uint(f);
    u += 0x7fffu + ((u >> 16) & 1u);
    return (unsigned short)(u >> 16);
}

__device__ __forceinline__ void gload16(const unsigned short* g, unsigned short* l) {
    __builtin_amdgcn_global_load_lds(
        (const __attribute__((address_space(1))) void*)g,
        (__attribute__((address_space(3))) void*)l, 16, 0, 0);
}

// ---------------- Kernel 1: normalize rows + positives ----------------
__global__ __launch_bounds__(256) void normalize_pos_kernel(
    const float* __restrict__ ei, const float* __restrict__ ej,
    unsigned short* __restrict__ reps, float* __restrict__ pos) {
    const int t = threadIdx.x & 63;
    const int i = blockIdx.x * 4 + (threadIdx.x >> 6);

    const float4* ri = (const float4*)(ei + (size_t)i * DIM);
    const float4* rj = (const float4*)(ej + (size_t)i * DIM);
    float4 a0 = ri[t], a1 = ri[t + 64];
    float4 b0 = rj[t], b1 = rj[t + 64];

    float si  = a0.x*a0.x + a0.y*a0.y + a0.z*a0.z + a0.w*a0.w
              + a1.x*a1.x + a1.y*a1.y + a1.z*a1.z + a1.w*a1.w;
    float sj  = b0.x*b0.x + b0.y*b0.y + b0.z*b0.z + b0.w*b0.w
              + b1.x*b1.x + b1.y*b1.y + b1.z*b1.z + b1.w*b1.w;
    float dij = a0.x*b0.x + a0.y*b0.y + a0.z*b0.z + a0.w*b0.w
              + a1.x*b1.x + a1.y*b1.y + a1.z*b1.z + a1.w*b1.w;

    #pragma unroll
    for (int m = 1; m < 64; m <<= 1) {
        si  += __shfl_xor(si,  m);
        sj  += __shfl_xor(sj,  m);
        dij += __shfl_xor(dij, m);
    }
    float invi = 1.0f / fmaxf(sqrtf(si), 1e-12f);
    float invj = 1.0f / fmaxf(sqrtf(sj), 1e-12f);

    ushort4 o0, o1, p0, p1;
    o0.x = f2bf(a0.x*invi); o0.y = f2bf(a0.y*invi); o0.z = f2bf(a0.z*invi); o0.w = f2bf(a0.w*invi);
    o1.x = f2bf(a1.x*invi); o1.y = f2bf(a1.y*invi); o1.z = f2bf(a1.z*invi); o1.w = f2bf(a1.w*invi);
    p0.x = f2bf(b0.x*invj); p0.y = f2bf(b0.y*invj); p0.z = f2bf(b0.z*invj); p0.w = f2bf(b0.w*invj);
    p1.x = f2bf(b1.x*invj); p1.y = f2bf(b1.y*invj); p1.z = f2bf(b1.z*invj); p1.w = f2bf(b1.w*invj);

    ushort4* wi = (ushort4*)(reps + (size_t)i * DIM);
    ushort4* wj = (ushort4*)(reps + (size_t)(BATCH + i) * DIM);
    wi[t] = o0; wi[t + 64] = o1;
    wj[t] = p0; wj[t + 64] = p1;
    if (t == 0) pos[i] = dij * invi * invj;
}

// ---------------- Kernel 2: triangle 256x256 cells (diag folded) ----------
// r6's proven schedule: BK=32, ring-4 LDS slots (128 KB), depth-3 prefetch,
// counted vmcnt(8/4/0), ONE barrier per K-step. CHANGE vs r6: no manual
// lgkmcnt(0)/sched_barrier pin before the MFMA cluster -> compiler emits
// counted lgkm waits and interleaves the 12 ds_reads with the 32 MFMAs.
__global__ __launch_bounds__(512, 2) void simsum_kernel(
    const unsigned short* __restrict__ reps, float* __restrict__ partials) {
    __shared__ unsigned short lds[4][16384];   // slot: A 256x32 | B 256x32 (32 KB)

    int bid = (blockIdx.x & 7) * (NBLK / 8) + (blockIdx.x >> 3);  // 528 = 8*66
    int rc = 0, b = bid;
    while (b >= NCH - rc) { b -= NCH - rc; ++rc; }
    const int cc = rc + b;                    // rc <= cc
    const bool isDiag = (rc == cc);

    const int tid  = threadIdx.x;
    const int lane = tid & 63;
    const int wave = tid >> 6;
    const int wr = wave >> 2, wc = wave & 3;
    const int s = lane & 15, q = lane >> 4;
    const int rowBase = rc * TILE, colBase = cc * TILE;

    // staging: wave w owns rows [32w, 32w+32) of A and B; pre-swizzled source
    const int lr = lane >> 2;                                  // row-in-16
    const int g8 = (((lane & 3) ^ ((lane >> 2) & 3) ^ (lane >> 4)) & 3) * 8;
    const unsigned short* gAw = reps + (size_t)(rowBase + wave * 32 + lr) * DIM + g8;
    const unsigned short* gBw = reps + (size_t)(colBase + wave * 32 + lr) * DIM + g8;

    // ds_read swizzled byte offsets (r6-verified conflict-free)
    const int sig  = ((s & 3) ^ (s >> 2)) & 3;
    const int koS  = ((q ^ sig) & 3) << 4;
    const int aoff = (wr * 128 + s) * 64 + koS;                // + m*1024
    const int boff = 16384 + (wc * 64 + s) * 64 + koS;         // + n*1024

    f32x4 acc[8][4];
    #pragma unroll
    for (int m = 0; m < 8; ++m)
        #pragma unroll
        for (int n = 0; n < 4; ++n) acc[m][n] = (f32x4){0.f,0.f,0.f,0.f};

#define STAGE(t) do { \
        const int _kb = (t) * 32; \
        unsigned short* _sb = &lds[(t) & 3][0]; \
        gload16(gAw + _kb,            _sb + wave * 1024); \
        gload16(gAw + 16 * DIM + _kb, _sb + wave * 1024 + 512); \
        gload16(gBw + _kb,            _sb + 8192 + wave * 1024); \
        gload16(gBw + 16 * DIM + _kb, _sb + 8192 + wave * 1024 + 512); \
    } while (0)

    // prologue: stage K-steps 0,1,2 (12 loads/wave outstanding)
    STAGE(0); STAGE(1); STAGE(2);

    #pragma unroll
    for (int t = 0; t < 16; ++t) {
        // publish slot t (its 4 loads are the oldest of the 12 outstanding)
        if (t < 14)       { asm volatile("s_waitcnt vmcnt(8)" ::: "memory"); }
        else if (t == 14) { asm volatile("s_waitcnt vmcnt(4)" ::: "memory"); }
        else              { asm volatile("s_waitcnt vmcnt(0)" ::: "memory"); }
        __builtin_amdgcn_s_barrier();
        __builtin_amdgcn_sched_barrier(0);   // keep reads below the publish point

        // stage K-step t+3 into slot (t-1)&3 (readers done before this barrier)
        if (t + 3 < 16) STAGE(t + 3);

        const char* base = (const char*)&lds[t & 3][0];
        bf16x8 af[4], ag[4], bf[4];
        #pragma unroll
        for (int m = 0; m < 4; ++m) af[m] = *(const bf16x8*)(base + aoff + m * 1024);
        #pragma unroll
        for (int n = 0; n < 4; ++n) bf[n] = *(const bf16x8*)(base + boff + n * 1024);
        #pragma unroll
        for (int m = 0; m < 4; ++m) ag[m] = *(const bf16x8*)(base + aoff + (4 + m) * 1024);

        // NO manual lgkm(0)/sched_barrier: compiler interleaves reads & MFMAs
        __builtin_amdgcn_s_setprio(1);
        #pragma unroll
        for (int m = 0; m < 4; ++m)
            #pragma unroll
            for (int n = 0; n < 4; ++n)
                acc[m][n] = __builtin_amdgcn_mfma_f32_16x16x32_bf16(
                    af[m], bf[n], acc[m][n], 0, 0, 0);
        #pragma unroll
        for (int m = 0; m < 4; ++m)
            #pragma unroll
            for (int n = 0; n < 4; ++n)
                acc[4 + m][n] = __builtin_amdgcn_mfma_f32_16x16x32_bf16(
                    ag[m], bf[n], acc[4 + m][n], 0, 0, 0);
        __builtin_amdgcn_s_setprio(0);
    }
#undef STAGE

    // ---- epilogue: exp(sim/T); diag masked; row + col sums ----
    const float SCALE = 2.8853900817779268f;   // 2/ln2
    float* red = (float*)lds;                  // [4][256] rowsum | [2][256] colsum
    __syncthreads();
    float colacc[4] = {0.f,0.f,0.f,0.f};
    #pragma unroll
    for (int m = 0; m < 8; ++m) {
        const int lrow0 = wr * 128 + m * 16 + (q << 2);
        const int grow0 = rowBase + lrow0;
        float rs[4] = {0.f,0.f,0.f,0.f};
        #pragma unroll
        for (int n = 0; n < 4; ++n) {
            const int gcol = colBase + wc * 64 + n * 16 + s;
            #pragma unroll
            for (int j = 0; j < 4; ++j) {
                float e = exp2f(acc[m][n][j] * SCALE);
                if (isDiag && (grow0 + j == gcol)) e = 0.f;
                rs[j] += e;
                colacc[n] += e;
            }
        }
        #pragma unroll
        for (int j = 0; j < 4; ++j) {
            float v = rs[j];
            v += __shfl_xor(v, 1); v += __shfl_xor(v, 2);
            v += __shfl_xor(v, 4); v += __shfl_xor(v, 8);
            if (s == 0) red[wc * 256 + lrow0 + j] = v;
        }
    }
    #pragma unroll
    for (int n = 0; n < 4; ++n) {
        float v = colacc[n];
        v += __shfl_xor(v, 16); v += __shfl_xor(v, 32);
        if (q == 0) red[1024 + wr * 256 + wc * 64 + n * 16 + s] = v;
    }
    __syncthreads();
    if (tid < 256) {
        partials[(size_t)cc * NROW + rowBase + tid] =
            red[tid] + red[256 + tid] + red[512 + tid] + red[768 + tid];
        if (!isDiag)
            partials[(size_t)rc * NROW + colBase + tid] =
                red[1024 + tid] + red[1280 + tid];
    }
}

// ---------------- Kernel 3a: per-row loss partial sums ----------------
__global__ __launch_bounds__(256) void rowloss_kernel(
    const float* __restrict__ partials, const float* __restrict__ pos,
    double* __restrict__ blocksum) {
    const int t = threadIdx.x;
    const int r = blockIdx.x * 256 + t;
    float denom = 0.f;
    #pragma unroll 8
    for (int c = 0; c < NSLOT; ++c)
        denom += partials[(size_t)c * NROW + r];
    double v = (double)(logf(denom) - 2.0f * pos[r & (BATCH - 1)]);
    __shared__ double redl[256];
    redl[t] = v;
    __syncthreads();
    for (int off = 128; off > 0; off >>= 1) {
        if (t < off) redl[t] += redl[t + off];
        __syncthreads();
    }
    if (t == 0) blocksum[blockIdx.x] = redl[0];
}

__global__ void final2_kernel(const double* __restrict__ blocksum,
                              float* __restrict__ out) {
    if (threadIdx.x == 0) {
        double ssum = 0.0;
        #pragma unroll
        for (int i = 0; i < NROW / 256; ++i) ssum += blocksum[i];
        out[0] = (float)(ssum / (double)NROW);
    }
}

extern "C" void kernel_launch(void* const* d_in, const int* in_sizes, int n_in,
                              void* d_out, int out_size, void* d_ws, size_t ws_size,
                              hipStream_t stream) {
    const float* ei = (const float*)d_in[0];
    const float* ej = (const float*)d_in[1];
    float* out = (float*)d_out;

    unsigned short* reps = (unsigned short*)d_ws;                       // 8 MB
    float* pos      = (float*)((char*)d_ws + (size_t)NROW * DIM * 2);   // 16 KB
    float* partials = pos + BATCH;                                      // 32*8192*4
    double* blocksum = (double*)(partials + (size_t)NSLOT * NROW);

    normalize_pos_kernel<<<BATCH / 4, 256, 0, stream>>>(ei, ej, reps, pos);
    simsum_kernel<<<NBLK, 512, 0, stream>>>(reps, partials);
    rowloss_kernel<<<NROW / 256, 256, 0, stream>>>(partials, pos, blocksum);
    final2_kernel<<<1, 64, 0, stream>>>(blocksum, out);
}

// Round 14
// 81.349 us; speedup vs baseline: 1.0560x; 1.0560x over previous
//
#include <hip/hip_runtime.h>

#define BATCH 4096
#define DIM   512
#define NROW  8192
#define TILE  128
#define NCH   64                      // 128-row/col chunks
#define NBLK  (NCH * (NCH + 1) / 2)   // 2080 triangle cells (incl. diagonal)
#define NSLOT 64

typedef __attribute__((ext_vector_type(8))) short bf16x8;
typedef __attribute__((ext_vector_type(4))) float f32x4;

__device__ inline unsigned short f2bf(float f) {
    unsigned int u = __float_as_uint(f);
    u += 0x7fffu + ((u >> 16) & 1u);
    return (unsigned short)(u >> 16);
}

__device__ __forceinline__ void gload16(const unsigned short* g, unsigned short* l) {
    __builtin_amdgcn_global_load_lds(
        (const __attribute__((address_space(1))) void*)g,
        (__attribute__((address_space(3))) void*)l, 16, 0, 0);
}

// ---------------- Kernel 1: normalize rows + positives ----------------
__global__ __launch_bounds__(256) void normalize_pos_kernel(
    const float* __restrict__ ei, const float* __restrict__ ej,
    unsigned short* __restrict__ reps, float* __restrict__ pos) {
    const int t = threadIdx.x & 63;
    const int i = blockIdx.x * 4 + (threadIdx.x >> 6);

    const float4* ri = (const float4*)(ei + (size_t)i * DIM);
    const float4* rj = (const float4*)(ej + (size_t)i * DIM);
    float4 a0 = ri[t], a1 = ri[t + 64];
    float4 b0 = rj[t], b1 = rj[t + 64];

    float si  = a0.x*a0.x + a0.y*a0.y + a0.z*a0.z + a0.w*a0.w
              + a1.x*a1.x + a1.y*a1.y + a1.z*a1.z + a1.w*a1.w;
    float sj  = b0.x*b0.x + b0.y*b0.y + b0.z*b0.z + b0.w*b0.w
              + b1.x*b1.x + b1.y*b1.y + b1.z*b1.z + b1.w*b1.w;
    float dij = a0.x*b0.x + a0.y*b0.y + a0.z*b0.z + a0.w*b0.w
              + a1.x*b1.x + a1.y*b1.y + a1.z*b1.z + a1.w*b1.w;

    #pragma unroll
    for (int m = 1; m < 64; m <<= 1) {
        si  += __shfl_xor(si,  m);
        sj  += __shfl_xor(sj,  m);
        dij += __shfl_xor(dij, m);
    }
    float invi = 1.0f / fmaxf(sqrtf(si), 1e-12f);
    float invj = 1.0f / fmaxf(sqrtf(sj), 1e-12f);

    ushort4 o0, o1, p0, p1;
    o0.x = f2bf(a0.x*invi); o0.y = f2bf(a0.y*invi); o0.z = f2bf(a0.z*invi); o0.w = f2bf(a0.w*invi);
    o1.x = f2bf(a1.x*invi); o1.y = f2bf(a1.y*invi); o1.z = f2bf(a1.z*invi); o1.w = f2bf(a1.w*invi);
    p0.x = f2bf(b0.x*invj); p0.y = f2bf(b0.y*invj); p0.z = f2bf(b0.z*invj); p0.w = f2bf(b0.w*invj);
    p1.x = f2bf(b1.x*invj); p1.y = f2bf(b1.y*invj); p1.z = f2bf(b1.z*invj); p1.w = f2bf(b1.w*invj);

    ushort4* wi = (ushort4*)(reps + (size_t)i * DIM);
    ushort4* wj = (ushort4*)(reps + (size_t)(BATCH + i) * DIM);
    wi[t] = o0; wi[t + 64] = o1;
    wj[t] = p0; wj[t + 64] = p1;
    if (t == 0) pos[i] = dij * invi * invj;
}

// ---------------- Kernel 2: triangle 128x128 cells, 2 blocks/CU ----------
// r6's exact machinery at half tile: BK=32, ring-4 LDS slots (64 KB ->
// 2 blocks/CU), depth-3 prefetch, counted vmcnt(8/4/0), ONE barrier/K-step,
// lgkm(0)+sched_barrier pin (r13 proved removing it costs 33%), setprio.
// Inter-block wave overlap (m114/m97: co-resident blocks) covers stalls.
__global__ __launch_bounds__(256, 2) void simsum_kernel(
    const unsigned short* __restrict__ reps, float* __restrict__ partials) {
    __shared__ unsigned short lds[4][8192];   // slot: A 128x32 | B 128x32 (16 KB)

    int bid = (blockIdx.x & 7) * (NBLK / 8) + (blockIdx.x >> 3);  // 2080 = 8*260
    int rc = 0, b = bid;
    while (b >= NCH - rc) { b -= NCH - rc; ++rc; }
    const int cc = rc + b;                    // rc <= cc
    const bool isDiag = (rc == cc);

    const int tid  = threadIdx.x;
    const int lane = tid & 63;
    const int wave = tid >> 6;                // 0..3
    const int wr = wave >> 1, wc = wave & 1;
    const int s = lane & 15, q = lane >> 4;
    const int rowBase = rc * TILE, colBase = cc * TILE;

    // staging: wave w owns rows [32w, 32w+32) of A and B; pre-swizzled source
    const int lr = lane >> 2;                                  // row-in-16
    const int g8 = (((lane & 3) ^ ((lane >> 2) & 3) ^ (lane >> 4)) & 3) * 8;
    const unsigned short* gAw = reps + (size_t)(rowBase + wave * 32 + lr) * DIM + g8;
    const unsigned short* gBw = reps + (size_t)(colBase + wave * 32 + lr) * DIM + g8;

    // ds_read swizzled byte offsets (r6-verified pattern; 64 B rows)
    const int sig  = ((s & 3) ^ (s >> 2)) & 3;
    const int koS  = ((q ^ sig) & 3) << 4;
    const int aoff = (wr * 64 + s) * 64 + koS;                 // + m*1024
    const int boff = 8192 + (wc * 64 + s) * 64 + koS;          // + n*1024

    f32x4 acc[4][4];
    #pragma unroll
    for (int m = 0; m < 4; ++m)
        #pragma unroll
        for (int n = 0; n < 4; ++n) acc[m][n] = (f32x4){0.f,0.f,0.f,0.f};

#define STAGE(t) do { \
        const int _kb = (t) * 32; \
        unsigned short* _sb = &lds[(t) & 3][0]; \
        gload16(gAw + _kb,            _sb + wave * 1024); \
        gload16(gAw + 16 * DIM + _kb, _sb + wave * 1024 + 512); \
        gload16(gBw + _kb,            _sb + 4096 + wave * 1024); \
        gload16(gBw + 16 * DIM + _kb, _sb + 4096 + wave * 1024 + 512); \
    } while (0)

    // prologue: stage K-steps 0,1,2 (12 loads/wave outstanding)
    STAGE(0); STAGE(1); STAGE(2);

    #pragma unroll
    for (int t = 0; t < 16; ++t) {
        // publish slot t (its 4 loads are the oldest of the outstanding set)
        if (t < 14)       { asm volatile("s_waitcnt vmcnt(8)" ::: "memory"); }
        else if (t == 14) { asm volatile("s_waitcnt vmcnt(4)" ::: "memory"); }
        else              { asm volatile("s_waitcnt vmcnt(0)" ::: "memory"); }
        __builtin_amdgcn_s_barrier();
        __builtin_amdgcn_sched_barrier(0);

        // stage K-step t+3 into slot (t-1)&3 (readers done before this barrier)
        if (t + 3 < 16) STAGE(t + 3);

        const char* base = (const char*)&lds[t & 3][0];
        bf16x8 af[4], bf[4];
        #pragma unroll
        for (int m = 0; m < 4; ++m) af[m] = *(const bf16x8*)(base + aoff + m * 1024);
        #pragma unroll
        for (int n = 0; n < 4; ++n) bf[n] = *(const bf16x8*)(base + boff + n * 1024);

        asm volatile("s_waitcnt lgkmcnt(0)" ::: "memory");   // the pin (keep!)
        __builtin_amdgcn_sched_barrier(0);
        __builtin_amdgcn_s_setprio(1);
        #pragma unroll
        for (int m = 0; m < 4; ++m)
            #pragma unroll
            for (int n = 0; n < 4; ++n)
                acc[m][n] = __builtin_amdgcn_mfma_f32_16x16x32_bf16(
                    af[m], bf[n], acc[m][n], 0, 0, 0);
        __builtin_amdgcn_s_setprio(0);
    }
#undef STAGE

    // ---- epilogue: exp(sim/T); diag masked; row + col sums ----
    const float SCALE = 2.8853900817779268f;   // 2/ln2
    float* red = (float*)lds;                  // [2][128] rowsum | [2][128] colsum
    __syncthreads();
    float colacc[4] = {0.f,0.f,0.f,0.f};
    #pragma unroll
    for (int m = 0; m < 4; ++m) {
        const int lrow0 = wr * 64 + m * 16 + (q << 2);
        const int grow0 = rowBase + lrow0;
        float rs[4] = {0.f,0.f,0.f,0.f};
        #pragma unroll
        for (int n = 0; n < 4; ++n) {
            const int gcol = colBase + wc * 64 + n * 16 + s;
            #pragma unroll
            for (int j = 0; j < 4; ++j) {
                float e = exp2f(acc[m][n][j] * SCALE);
                if (isDiag && (grow0 + j == gcol)) e = 0.f;
                rs[j] += e;
                colacc[n] += e;
            }
        }
        #pragma unroll
        for (int j = 0; j < 4; ++j) {
            float v = rs[j];
            v += __shfl_xor(v, 1); v += __shfl_xor(v, 2);
            v += __shfl_xor(v, 4); v += __shfl_xor(v, 8);
            if (s == 0) red[wc * 128 + lrow0 + j] = v;
        }
    }
    #pragma unroll
    for (int n = 0; n < 4; ++n) {
        float v = colacc[n];
        v += __shfl_xor(v, 16); v += __shfl_xor(v, 32);
        if (q == 0) red[256 + wr * 128 + wc * 64 + n * 16 + s] = v;
    }
    __syncthreads();
    if (tid < TILE) {
        partials[(size_t)cc * NROW + rowBase + tid] = red[tid] + red[128 + tid];
        if (!isDiag)
            partials[(size_t)rc * NROW + colBase + tid] =
                red[256 + tid] + red[384 + tid];
    }
}

// ---------------- Kernel 3a: per-row loss partial sums ----------------
__global__ __launch_bounds__(256) void rowloss_kernel(
    const float* __restrict__ partials, const float* __restrict__ pos,
    double* __restrict__ blocksum) {
    const int t = threadIdx.x;
    const int r = blockIdx.x * 256 + t;
    float denom = 0.f;
    #pragma unroll 16
    for (int c = 0; c < NSLOT; ++c)
        denom += partials[(size_t)c * NROW + r];
    double v = (double)(logf(denom) - 2.0f * pos[r & (BATCH - 1)]);
    __shared__ double redl[256];
    redl[t] = v;
    __syncthreads();
    for (int off = 128; off > 0; off >>= 1) {
        if (t < off) redl[t] += redl[t + off];
        __syncthreads();
    }
    if (t == 0) blocksum[blockIdx.x] = redl[0];
}

__global__ void final2_kernel(const double* __restrict__ blocksum,
                              float* __restrict__ out) {
    if (threadIdx.x == 0) {
        double ssum = 0.0;
        #pragma unroll
        for (int i = 0; i < NROW / 256; ++i) ssum += blocksum[i];
        out[0] = (float)(ssum / (double)NROW);
    }
}

extern "C" void kernel_launch(void* const* d_in, const int* in_sizes, int n_in,
                              void* d_out, int out_size, void* d_ws, size_t ws_size,
                              hipStream_t stream) {
    const float* ei = (const float*)d_in[0];
    const float* ej = (const float*)d_in[1];
    float* out = (float*)d_out;

    unsigned short* reps = (unsigned short*)d_ws;                       // 8 MB
    float* pos      = (float*)((char*)d_ws + (size_t)NROW * DIM * 2);   // 16 KB
    float* partials = pos + BATCH;                                      // 64*8192*4 = 2 MB
    double* blocksum = (double*)(partials + (size_t)NSLOT * NROW);

    normalize_pos_kernel<<<BATCH / 4, 256, 0, stream>>>(ei, ej, reps, pos);
    simsum_kernel<<<NBLK, 256, 0, stream>>>(reps, partials);
    rowloss_kernel<<<NROW / 256, 256, 0, stream>>>(partials, pos, blocksum);
    final2_kernel<<<1, 64, 0, stream>>>(blocksum, out);
}

// Round 15
// 73.799 us; speedup vs baseline: 1.1640x; 1.1023x over previous
//
#include <hip/hip_runtime.h>

#define BATCH 4096
#define DIM   512
#define NROW  8192
#define TILE  128
#define NCH   64                      // 128-row/col chunks
#define NBLK  (NCH * (NCH + 1) / 2)   // 2080 triangle cells (incl. diagonal)
#define NSLOT 64

typedef __attribute__((ext_vector_type(8))) short bf16x8;
typedef __attribute__((ext_vector_type(4))) float f32x4;

__device__ inline unsigned short f2bf(float f) {
    unsigned int u = __float_as_uint(f);
    u += 0x7fffu + ((u >> 16) & 1u);
    return (unsigned short)(u >> 16);
}

__device__ __forceinline__ void gload16(const unsigned short* g, unsigned short* l) {
    __builtin_amdgcn_global_load_lds(
        (const __attribute__((address_space(1))) void*)g,
        (__attribute__((address_space(3))) void*)l, 16, 0, 0);
}

// ---------------- Kernel 1: normalize rows + positives ----------------
__global__ __launch_bounds__(256) void normalize_pos_kernel(
    const float* __restrict__ ei, const float* __restrict__ ej,
    unsigned short* __restrict__ reps, float* __restrict__ pos) {
    const int t = threadIdx.x & 63;
    const int i = blockIdx.x * 4 + (threadIdx.x >> 6);

    const float4* ri = (const float4*)(ei + (size_t)i * DIM);
    const float4* rj = (const float4*)(ej + (size_t)i * DIM);
    float4 a0 = ri[t], a1 = ri[t + 64];
    float4 b0 = rj[t], b1 = rj[t + 64];

    float si  = a0.x*a0.x + a0.y*a0.y + a0.z*a0.z + a0.w*a0.w
              + a1.x*a1.x + a1.y*a1.y + a1.z*a1.z + a1.w*a1.w;
    float sj  = b0.x*b0.x + b0.y*b0.y + b0.z*b0.z + b0.w*b0.w
              + b1.x*b1.x + b1.y*b1.y + b1.z*b1.z + b1.w*b1.w;
    float dij = a0.x*b0.x + a0.y*b0.y + a0.z*b0.z + a0.w*b0.w
              + a1.x*b1.x + a1.y*b1.y + a1.z*b1.z + a1.w*b1.w;

    #pragma unroll
    for (int m = 1; m < 64; m <<= 1) {
        si  += __shfl_xor(si,  m);
        sj  += __shfl_xor(sj,  m);
        dij += __shfl_xor(dij, m);
    }
    float invi = 1.0f / fmaxf(sqrtf(si), 1e-12f);
    float invj = 1.0f / fmaxf(sqrtf(sj), 1e-12f);

    ushort4 o0, o1, p0, p1;
    o0.x = f2bf(a0.x*invi); o0.y = f2bf(a0.y*invi); o0.z = f2bf(a0.z*invi); o0.w = f2bf(a0.w*invi);
    o1.x = f2bf(a1.x*invi); o1.y = f2bf(a1.y*invi); o1.z = f2bf(a1.z*invi); o1.w = f2bf(a1.w*invi);
    p0.x = f2bf(b0.x*invj); p0.y = f2bf(b0.y*invj); p0.z = f2bf(b0.z*invj); p0.w = f2bf(b0.w*invj);
    p1.x = f2bf(b1.x*invj); p1.y = f2bf(b1.y*invj); p1.z = f2bf(b1.z*invj); p1.w = f2bf(b1.w*invj);

    ushort4* wi = (ushort4*)(reps + (size_t)i * DIM);
    ushort4* wj = (ushort4*)(reps + (size_t)(BATCH + i) * DIM);
    wi[t] = o0; wi[t + 64] = o1;
    wj[t] = p0; wj[t + 64] = p1;
    if (t == 0) pos[i] = dij * invi * invj;
}

// ---------------- Kernel 2: triangle 128x128 cells, m97-clone ----------
// Faithful m97 structure (874-912 TF HW-verified): 4 waves, 64x64/wave,
// BK=32, SINGLE 16 KB LDS buffer, plain 2-__syncthreads K-loop, no inline
// asm -- compiler emits counted lgkm waits + the pre-barrier vmcnt drain,
// and 4-5 co-resident blocks/CU (16 KB LDS) cover the stalls (m114).
// Additions kept from this session: zero-conflict swizzle pair (r6-verified),
// triangle grid w/ diag mask + row/col dual-sum epilogue (r12-verified).
__global__ __launch_bounds__(256) void simsum_kernel(
    const unsigned short* __restrict__ reps, float* __restrict__ partials) {
    __shared__ unsigned short lds[8192];   // A [128][32] | B [128][32] bf16

    int bid = (blockIdx.x & 7) * (NBLK / 8) + (blockIdx.x >> 3);  // 2080 = 8*260
    int rc = 0, b = bid;
    while (b >= NCH - rc) { b -= NCH - rc; ++rc; }
    const int cc = rc + b;                    // rc <= cc
    const bool isDiag = (rc == cc);

    const int tid  = threadIdx.x;
    const int lane = tid & 63;
    const int wave = tid >> 6;                // 0..3
    const int wr = wave >> 1, wc = wave & 1;
    const int s = lane & 15, q = lane >> 4;
    const int rowBase = rc * TILE, colBase = cc * TILE;

    // staging: wave w owns rows [32w, 32w+32) of A and B; pre-swizzled source
    const int lr = lane >> 2;                                  // row-in-16
    const int g8 = (((lane & 3) ^ ((lane >> 2) & 3) ^ (lane >> 4)) & 3) * 8;
    const unsigned short* gAw = reps + (size_t)(rowBase + wave * 32 + lr) * DIM + g8;
    const unsigned short* gBw = reps + (size_t)(colBase + wave * 32 + lr) * DIM + g8;

    // ds_read swizzled byte offsets (r6-verified conflict-free; 64 B rows)
    const int sig  = ((s & 3) ^ (s >> 2)) & 3;
    const int koS  = ((q ^ sig) & 3) << 4;
    const int aoff = (wr * 64 + s) * 64 + koS;                 // + m*1024
    const int boff = 8192 + (wc * 64 + s) * 64 + koS;          // + n*1024 (B at byte 8192)

    f32x4 acc[4][4];
    #pragma unroll
    for (int m = 0; m < 4; ++m)
        #pragma unroll
        for (int n = 0; n < 4; ++n) acc[m][n] = (f32x4){0.f,0.f,0.f,0.f};

    for (int t = 0; t < 16; ++t) {
        __syncthreads();                       // prev readers done: safe to overwrite
        {
            const int kb = t * 32;
            gload16(gAw + kb,            lds + wave * 1024);
            gload16(gAw + 16 * DIM + kb, lds + wave * 1024 + 512);
            gload16(gBw + kb,            lds + 4096 + wave * 1024);
            gload16(gBw + 16 * DIM + kb, lds + 4096 + wave * 1024 + 512);
        }
        __syncthreads();                       // publish (compiler drains vmcnt)

        const char* base = (const char*)lds;
        bf16x8 af[4], bf[4];
        #pragma unroll
        for (int m = 0; m < 4; ++m) af[m] = *(const bf16x8*)(base + aoff + m * 1024);
        #pragma unroll
        for (int n = 0; n < 4; ++n) bf[n] = *(const bf16x8*)(base + boff + n * 1024);

        #pragma unroll
        for (int m = 0; m < 4; ++m)
            #pragma unroll
            for (int n = 0; n < 4; ++n)
                acc[m][n] = __builtin_amdgcn_mfma_f32_16x16x32_bf16(
                    af[m], bf[n], acc[m][n], 0, 0, 0);
    }

    // ---- epilogue: exp(sim/T); diag masked; row + col sums ----
    const float SCALE = 2.8853900817779268f;   // 2/ln2
    float* red = (float*)lds;                  // [2][128] rowsum | [2][128] colsum
    __syncthreads();
    float colacc[4] = {0.f,0.f,0.f,0.f};
    #pragma unroll
    for (int m = 0; m < 4; ++m) {
        const int lrow0 = wr * 64 + m * 16 + (q << 2);
        const int grow0 = rowBase + lrow0;
        float rs[4] = {0.f,0.f,0.f,0.f};
        #pragma unroll
        for (int n = 0; n < 4; ++n) {
            const int gcol = colBase + wc * 64 + n * 16 + s;
            #pragma unroll
            for (int j = 0; j < 4; ++j) {
                float e = exp2f(acc[m][n][j] * SCALE);
                if (isDiag && (grow0 + j == gcol)) e = 0.f;
                rs[j] += e;
                colacc[n] += e;
            }
        }
        #pragma unroll
        for (int j = 0; j < 4; ++j) {
            float v = rs[j];
            v += __shfl_xor(v, 1); v += __shfl_xor(v, 2);
            v += __shfl_xor(v, 4); v += __shfl_xor(v, 8);
            if (s == 0) red[wc * 128 + lrow0 + j] = v;
        }
    }
    #pragma unroll
    for (int n = 0; n < 4; ++n) {
        float v = colacc[n];
        v += __shfl_xor(v, 16); v += __shfl_xor(v, 32);
        if (q == 0) red[256 + wr * 128 + wc * 64 + n * 16 + s] = v;
    }
    __syncthreads();
    if (tid < TILE) {
        partials[(size_t)cc * NROW + rowBase + tid] = red[tid] + red[128 + tid];
        if (!isDiag)
            partials[(size_t)rc * NROW + colBase + tid] =
                red[256 + tid] + red[384 + tid];
    }
}

// ---------------- Kernel 3a: per-row loss partial sums ----------------
__global__ __launch_bounds__(256) void rowloss_kernel(
    const float* __restrict__ partials, const float* __restrict__ pos,
    double* __restrict__ blocksum) {
    const int t = threadIdx.x;
    const int r = blockIdx.x * 256 + t;
    float denom = 0.f;
    #pragma unroll 16
    for (int c = 0; c < NSLOT; ++c)
        denom += partials[(size_t)c * NROW + r];
    double v = (double)(logf(denom) - 2.0f * pos[r & (BATCH - 1)]);
    __shared__ double redl[256];
    redl[t] = v;
    __syncthreads();
    for (int off = 128; off > 0; off >>= 1) {
        if (t < off) redl[t] += redl[t + off];
        __syncthreads();
    }
    if (t == 0) blocksum[blockIdx.x] = redl[0];
}

__global__ void final2_kernel(const double* __restrict__ blocksum,
                              float* __restrict__ out) {
    if (threadIdx.x == 0) {
        double ssum = 0.0;
        #pragma unroll
        for (int i = 0; i < NROW / 256; ++i) ssum += blocksum[i];
        out[0] = (float)(ssum / (double)NROW);
    }
}

extern "C" void kernel_launch(void* const* d_in, const int* in_sizes, int n_in,
                              void* d_out, int out_size, void* d_ws, size_t ws_size,
                              hipStream_t stream) {
    const float* ei = (const float*)d_in[0];
    const float* ej = (const float*)d_in[1];
    float* out = (float*)d_out;

    unsigned short* reps = (unsigned short*)d_ws;                       // 8 MB
    float* pos      = (float*)((char*)d_ws + (size_t)NROW * DIM * 2);   // 16 KB
    float* partials = pos + BATCH;                                      // 64*8192*4 = 2 MB
    double* blocksum = (double*)(partials + (size_t)NSLOT * NROW);

    normalize_pos_kernel<<<BATCH / 4, 256, 0, stream>>>(ei, ej, reps, pos);
    simsum_kernel<<<NBLK, 256, 0, stream>>>(reps, partials);
    rowloss_kernel<<<NROW / 256, 256, 0, stream>>>(partials, pos, blocksum);
    final2_kernel<<<1, 64, 0, stream>>>(blocksum, out);
}